// Round 9
// baseline (171.031 us; speedup 1.0000x reference)
//
#include <hip/hip_runtime.h>
#include <math.h>

#define NA 49152      // 64*64*12 anchors
#define NB 16
#define CHUNK 3072    // anchors per block
#define EPS 1e-3f     // decision-boundary guard; fast-sim error <= ~1e-4

__device__ __forceinline__ void st4(float* p, float a, float b, float c, float d) {
  *reinterpret_cast<float4*>(p) = make_float4(a, b, c, d);
}

__constant__ float RP[21][2] = {
  {213.33335876464844f, 124.50563049316406f},
  {190.504638671875f,   115.11840057373047f},
  {169.9791717529297f,  101.77180480957031f},
  {146.72341918945312f, 96.25749206542969f},
  {128.86770629882812f, 87.2344970703125f},
  {150.34292602539062f, 101.61070251464844f},
  {119.29926300048828f, 98.73982238769531f},
  {100.03463745117188f, 99.74459838867188f},
  {82.62400817871094f,  101.2509536743164f},
  {148.91049194335938f, 112.71517181396484f},
  {114.37303161621094f, 113.20121002197266f},
  {91.90096282958984f,  116.49812316894531f},
  {74.75020599365234f,  119.37875366210938f},
  {149.59658813476562f, 124.09295654296875f},
  {119.72419738769531f, 126.36898040771484f},
  {99.59107208251953f,  129.40196228027344f},
  {82.82524108886719f,  131.584228515625f},
  {154.55911254882812f, 135.07681274414062f},
  {133.8833770751953f,  140.85983276367188f},
  {120.45906066894531f, 145.40306091308594f},
  {106.21541595458984f, 150.072265625f}
};

// numpy pairwise-sum (n=21) replica for REF_POSE.mean(axis=0)
__device__ __forceinline__ void ref_center(float& cx, float& cy) {
  #pragma clang fp contract(off)
  float rx[8], ry[8];
  #pragma unroll
  for (int j = 0; j < 8; ++j) {
    rx[j] = RP[j][0] + RP[j + 8][0];
    ry[j] = RP[j][1] + RP[j + 8][1];
  }
  float sx = ((rx[0] + rx[1]) + (rx[2] + rx[3])) + ((rx[4] + rx[5]) + (rx[6] + rx[7]));
  float sy = ((ry[0] + ry[1]) + (ry[2] + ry[3])) + ((ry[4] + ry[5]) + (ry[6] + ry[7]));
  #pragma unroll
  for (int j = 16; j < 21; ++j) { sx += RP[j][0]; sy += RP[j][1]; }
  cx = sx / 21.0f;
  cy = sy / 21.0f;
}

// base pose (block-invariant): c + s*(RP-c)@R. Rotations by 0/90/180/270 are
// exactly negate/swap under f32. Anchor = base + shift (same association as ref).
__device__ __forceinline__ float2 base_pt(int p, int j, float cx, float cy) {
  #pragma clang fp contract(off)
  const int si = p >> 2, oi = p & 3;
  const float s = (si == 0) ? 0.25f : (si == 1 ? 0.5f : 1.0f);
  const float dx = s * (RP[j][0] - cx);
  const float dy = s * (RP[j][1] - cy);
  const float rx = (oi == 0) ? dx : (oi == 1 ? -dy : (oi == 2 ? -dx : dy));
  const float ry = (oi == 0) ? dy : (oi == 1 ? dx : (oi == 2 ? -dy : -dx));
  return make_float2(cx + rx, cy + ry);
}

// 256 blocks x 1024 threads: one block per CU, one contiguous write window per CU.
__global__ __launch_bounds__(1024, 4) void k_all(const float* __restrict__ gt,
                                                 const int* __restrict__ ht,
                                                 float* __restrict__ oa,
                                                 float* __restrict__ oins,
                                                 float* __restrict__ ol,
                                                 float* __restrict__ oo) {
  __shared__ float2 sb2[252];     // base poses [p][j]
  __shared__ float4 sg4[21];      // gt xy packed: (x0,y0,x1,y1) per kpt
  __shared__ float2 sv2[21];      // vis as 0/1 floats (v0,v1) per kpt
  __shared__ float sden[2], srden[2], snv[2];
  __shared__ int sht[2];
  __shared__ float4 sanc[CHUNK];  // per-anchor (shx, shy, p*21, decision code) - 48 KB

  const int tid = threadIdx.x;
  const int b = blockIdx.x >> 4;        // batch index
  const int c = blockIdx.x & 15;        // chunk within batch
  const int A0 = c * CHUNK;

  if (tid < 252) {
    float cx, cy; ref_center(cx, cy);
    sb2[tid] = base_pt(tid / 21, tid % 21, cx, cy);
  }
  if (tid < 21) {
    const float* g0 = gt + b * 126 + tid * 3;
    const float* g1 = g0 + 63;
    sg4[tid] = make_float4(g0[0], g0[1], g1[0], g1[1]);
    sv2[tid] = make_float2((g0[2] > 0.0f) ? 1.0f : 0.0f,
                           (g1[2] > 0.0f) ? 1.0f : 0.0f);
  }
  if (tid == 252 || tid == 253) {   // per-hand area/denominator
    const int h = tid - 252;
    const float* g = gt + b * 126 + h * 63;
    float mnx = g[0], mxx = g[0], mny = g[1], mxy = g[1];
    float nv = (g[2] > 0.0f) ? 1.0f : 0.0f;
    for (int j = 1; j < 21; ++j) {
      float x = g[j * 3], y = g[j * 3 + 1];
      mnx = fminf(mnx, x); mxx = fmaxf(mxx, x);
      mny = fminf(mny, y); mxy = fmaxf(mxy, y);
      nv += (g[j * 3 + 2] > 0.0f) ? 1.0f : 0.0f;
    }
    const float area = (mxx - mnx) * (mxy - mny);
    const float s2 = fmaxf(area, 1.0f);
    const float den = (2.0f * s2) * 0.01f;   // 2*s2*k2, k2 -> 0.01f in f32
    sden[h] = den;
    srden[h] = -1.0f / den;
    snv[h] = fmaxf(nv, 1.0f);
  }
  if (tid == 254 || tid == 255) sht[tid - 254] = ht[b * 2 + (tid - 254)];
  __syncthreads();

  // ---- decisions for 3 anchors per thread ----
  const float rd0 = srden[0], rd1 = srden[1];
  #pragma unroll
  for (int k = 0; k < 3; ++k) {
    const int aloc = k * 1024 + tid;
    const int a = A0 + aloc;
    const int p = a % 12;
    const int kc = a / 12;
    const float shx = 4.0f * (float)(kc & 63);
    const float shy = 4.0f * (float)(kc >> 6);
    const int pb = p * 21;

    // fast path: __expf-based sims
    bool inside = true;
    float s0f = 0.0f, s1f = 0.0f;
    #pragma unroll
    for (int j = 0; j < 21; ++j) {
      #pragma clang fp contract(off)
      const float2 bpv = sb2[pb + j];
      const float anx = bpv.x + shx;
      const float any = bpv.y + shy;
      inside = inside && (anx >= 0.0f) && (any >= 0.0f) &&
                         (anx < 256.0f) && (any < 256.0f);
      const float4 g = sg4[j];
      const float2 v = sv2[j];
      const float dx0 = anx - g.x, dy0 = any - g.y;
      const float dx1 = anx - g.z, dy1 = any - g.w;
      s0f += __expf((dx0 * dx0 + dy0 * dy0) * rd0) * v.x;
      s1f += __expf((dx1 * dx1 + dy1 * dy1) * rd1) * v.y;
    }
    float sim0 = s0f / snv[0];
    float sim1 = s1f / snv[1];
    const float mxf = fmaxf(sim0, sim1);
    const bool need_exact = (fabsf(mxf - 0.5f) < EPS) ||
                            ((mxf > 0.5f - EPS) && (fabsf(sim0 - sim1) < EPS));

    if (__builtin_expect(need_exact, 0)) {
      // exact fallback: bit-identical to round-1 (double exp, numpy tree)
      #pragma clang fp contract(off)
      float q0[8], q1[8];
      #pragma unroll
      for (int j = 0; j < 16; ++j) {
        const float2 bpv = sb2[pb + j];
        const float ax = bpv.x + shx, ay = bpv.y + shy;
        const float4 g = sg4[j];
        const float2 v = sv2[j];
        float dx0 = ax - g.x, dy0 = ay - g.y;
        float d20 = dx0 * dx0 + dy0 * dy0;
        float t0 = (float)::exp((double)(-d20 / sden[0])) * v.x;
        float dx1 = ax - g.z, dy1 = ay - g.w;
        float d21 = dx1 * dx1 + dy1 * dy1;
        float t1 = (float)::exp((double)(-d21 / sden[1])) * v.y;
        if (j < 8) { q0[j] = t0; q1[j] = t1; }
        else       { q0[j - 8] += t0; q1[j - 8] += t1; }
      }
      float s0 = ((q0[0] + q0[1]) + (q0[2] + q0[3])) + ((q0[4] + q0[5]) + (q0[6] + q0[7]));
      float s1 = ((q1[0] + q1[1]) + (q1[2] + q1[3])) + ((q1[4] + q1[5]) + (q1[6] + q1[7]));
      #pragma unroll
      for (int j = 16; j < 21; ++j) {
        const float2 bpv = sb2[pb + j];
        const float ax = bpv.x + shx, ay = bpv.y + shy;
        const float4 g = sg4[j];
        const float2 v = sv2[j];
        float dx0 = ax - g.x, dy0 = ay - g.y;
        float d20 = dx0 * dx0 + dy0 * dy0;
        s0 += (float)::exp((double)(-d20 / sden[0])) * v.x;
        float dx1 = ax - g.z, dy1 = ay - g.w;
        float d21 = dx1 * dx1 + dy1 * dy1;
        s1 += (float)::exp((double)(-d21 / sden[1])) * v.y;
      }
      sim0 = s0 / snv[0];
      sim1 = s1 / snv[1];
    }

    const int am = (sim1 > sim0) ? 1 : 0;   // argmax: first index wins ties
    const float mx = fmaxf(sim0, sim1);
    const bool pos = mx > 0.5f;
    const bool right = (am == 0) && pos && (sht[0] == 1) && inside;
    const bool left  = (am == 1) && pos && (sht[1] == 1) && inside;

    int cdec;         // -1 outside, 0 neg, 1 right, 2 left
    if (!inside)      cdec = -1;
    else if (right)   cdec = 1;
    else if (left)    cdec = 2;
    else              cdec = 0;
    sanc[aloc] = make_float4(shx, shy, (float)pb, (float)cdec);
  }
  __syncthreads();

  // ---- labels: 2304 float4, contiguous 36 KB window ----
  // (adds/subs only below: nothing can contract, no pragma needed)
  {
    float* lb = ol + ((size_t)b * NA + A0) * 3;
    #pragma unroll
    for (int i = 0; i < 3; ++i) {
      if (i == 2 && tid >= 256) break;
      const int idx = i * 1024 + tid;
      float r[4];
      #pragma unroll
      for (int kk = 0; kk < 4; ++kk) {
        const int q = idx * 4 + kk;
        const int al = q / 3;
        const int rr = q - al * 3;
        const int cc = (int)sanc[al].w;
        float v;
        if (cc < 0)       v = -1.0f;
        else if (rr == 0) v = (cc == 2) ? 1.0f : 0.0f;   // left
        else if (rr == 1) v = (cc == 0) ? 1.0f : 0.0f;   // neg
        else              v = (cc == 1) ? 1.0f : 0.0f;   // right
        r[kk] = v;
      }
      st4(lb + idx * 4, r[0], r[1], r[2], r[3]);
    }
  }

  // ---- offsets: 32256 float4, ONE contiguous 516 KB window per block ----
  // waves write ascending 16-KB super-chunks -> ~sequential stream per CU
  {
    float* ob = oo + ((size_t)b * NA + A0) * 42;
    int al = (2 * tid) / 21;            // one magic-div, then incremental
    int jj = (2 * tid) - al * 21;
    #pragma unroll
    for (int i = 0; i < 32; ++i) {
      if (i == 31 && tid >= 512) break;
      const int idx = i * 1024 + tid;
      const bool w1 = (jj + 1) >= 21;   // elem1 = elem0 + 1
      const int al1 = al + (w1 ? 1 : 0);
      const int j1 = w1 ? 0 : (jj + 1);
      float r[4];
      {
        const float4 sa = sanc[al];
        const int cc = (int)sa.w;
        const float2 bpv = sb2[(int)sa.z + jj];
        const float anx = bpv.x + sa.x, any = bpv.y + sa.y;
        const float4 g = sg4[jj];
        const bool has = (cc == 1) || (cc == 2);
        float tx = (cc == 2) ? g.z : g.x;
        float ty = (cc == 2) ? g.w : g.y;
        tx = has ? tx : 0.0f; ty = has ? ty : 0.0f;
        r[0] = (cc >= 0) ? (tx - anx) : 0.0f;
        r[1] = (cc >= 0) ? (ty - any) : 0.0f;
      }
      {
        const float4 sa = sanc[al1];
        const int cc = (int)sa.w;
        const float2 bpv = sb2[(int)sa.z + j1];
        const float anx = bpv.x + sa.x, any = bpv.y + sa.y;
        const float4 g = sg4[j1];
        const bool has = (cc == 1) || (cc == 2);
        float tx = (cc == 2) ? g.z : g.x;
        float ty = (cc == 2) ? g.w : g.y;
        tx = has ? tx : 0.0f; ty = has ? ty : 0.0f;
        r[2] = (cc >= 0) ? (tx - anx) : 0.0f;
        r[3] = (cc >= 0) ? (ty - any) : 0.0f;
      }
      st4(ob + idx * 4, r[0], r[1], r[2], r[3]);
      jj += 11; al += 97;                // advance by 2048 elements
      if (jj >= 21) { jj -= 21; ++al; }
    }
  }

  // ---- anchors: b-independent, distributed 1/16 per b; contiguous per block ----
  {
    float* ap = oa + (size_t)A0 * 42;
    #pragma unroll
    for (int i = 0; i < 2; ++i) {
      if (i == 1 && tid >= 992) break;
      const int idx = b * 2016 + i * 1024 + tid;
      const int e0 = idx * 2;
      const int al = e0 / 21;
      const int jj = e0 - al * 21;
      const bool w1 = (jj + 1) >= 21;
      const int al1 = al + (w1 ? 1 : 0);
      const int j1 = w1 ? 0 : (jj + 1);
      const float4 sa = sanc[al];
      const float2 bpv = sb2[(int)sa.z + jj];
      const float4 sb = sanc[al1];
      const float2 bq = sb2[(int)sb.z + j1];
      st4(ap + idx * 4, bpv.x + sa.x, bpv.y + sa.y,
                        bq.x + sb.x,  bq.y + sb.y);
    }
  }
  // ---- inside: 768 float4 per chunk, 48 per b (code>=0 <=> inside, b-indep) ----
  if (tid < 48) {
    const int t = b * 48 + tid;
    st4(oins + A0 + t * 4,
        (sanc[t * 4].w     >= 0.0f) ? 1.0f : 0.0f,
        (sanc[t * 4 + 1].w >= 0.0f) ? 1.0f : 0.0f,
        (sanc[t * 4 + 2].w >= 0.0f) ? 1.0f : 0.0f,
        (sanc[t * 4 + 3].w >= 0.0f) ? 1.0f : 0.0f);
  }
}

extern "C" void kernel_launch(void* const* d_in, const int* in_sizes, int n_in,
                              void* d_out, int out_size, void* d_ws, size_t ws_size,
                              hipStream_t stream) {
  (void)in_sizes; (void)n_in; (void)d_ws; (void)ws_size; (void)out_size;
  const float* gt = (const float*)d_in[0];   // (16,42,3) f32
  const int* ht = (const int*)d_in[1];       // (16,2) i32
  float* out = (float*)d_out;
  float* out_anchors = out;                                   // NA*42
  float* out_inside  = out + (size_t)NA * 42;                 // NA
  float* out_labels  = out + (size_t)NA * 43;                 // NB*NA*3
  float* out_offsets = out_labels + (size_t)NB * NA * 3;      // NB*NA*42

  hipLaunchKernelGGL(k_all, dim3(NB * 16), dim3(1024), 0, stream,
                     gt, ht, out_anchors, out_inside, out_labels, out_offsets);
}

// Round 10
// 170.972 us; speedup vs baseline: 1.0003x; 1.0003x over previous
//
#include <hip/hip_runtime.h>
#include <math.h>

#define NA 49152      // 64*64*12 anchors
#define NB 16
#define ABLOCKS 192   // NA / 256
#define EPS 1e-3f     // decision-boundary guard; fast-sim error <= ~1e-4
#define OF4B 516096   // offsets float4 per batch = NA*42/4
#define OF4  8257536  // offsets float4 total = NB*OF4B
#define AF4  516096   // anchors float4 = NA*42/4
#define IF4  12288    // inside float4 = NA/4

__device__ __forceinline__ void st4(float* p, float a, float b, float c, float d) {
  *reinterpret_cast<float4*>(p) = make_float4(a, b, c, d);
}

__constant__ float RP[21][2] = {
  {213.33335876464844f, 124.50563049316406f},
  {190.504638671875f,   115.11840057373047f},
  {169.9791717529297f,  101.77180480957031f},
  {146.72341918945312f, 96.25749206542969f},
  {128.86770629882812f, 87.2344970703125f},
  {150.34292602539062f, 101.61070251464844f},
  {119.29926300048828f, 98.73982238769531f},
  {100.03463745117188f, 99.74459838867188f},
  {82.62400817871094f,  101.2509536743164f},
  {148.91049194335938f, 112.71517181396484f},
  {114.37303161621094f, 113.20121002197266f},
  {91.90096282958984f,  116.49812316894531f},
  {74.75020599365234f,  119.37875366210938f},
  {149.59658813476562f, 124.09295654296875f},
  {119.72419738769531f, 126.36898040771484f},
  {99.59107208251953f,  129.40196228027344f},
  {82.82524108886719f,  131.584228515625f},
  {154.55911254882812f, 135.07681274414062f},
  {133.8833770751953f,  140.85983276367188f},
  {120.45906066894531f, 145.40306091308594f},
  {106.21541595458984f, 150.072265625f}
};

// numpy pairwise-sum (n=21) replica for REF_POSE.mean(axis=0)
__device__ __forceinline__ void ref_center(float& cx, float& cy) {
  #pragma clang fp contract(off)
  float rx[8], ry[8];
  #pragma unroll
  for (int j = 0; j < 8; ++j) {
    rx[j] = RP[j][0] + RP[j + 8][0];
    ry[j] = RP[j][1] + RP[j + 8][1];
  }
  float sx = ((rx[0] + rx[1]) + (rx[2] + rx[3])) + ((rx[4] + rx[5]) + (rx[6] + rx[7]));
  float sy = ((ry[0] + ry[1]) + (ry[2] + ry[3])) + ((ry[4] + ry[5]) + (ry[6] + ry[7]));
  #pragma unroll
  for (int j = 16; j < 21; ++j) { sx += RP[j][0]; sy += RP[j][1]; }
  cx = sx / 21.0f;
  cy = sy / 21.0f;
}

// base pose (block-invariant): c + s*(RP-c)@R. Rotations by 0/90/180/270 are
// exactly negate/swap under f32. Anchor = base + shift (same association as ref).
__device__ __forceinline__ float2 base_pt(int p, int j, float cx, float cy) {
  #pragma clang fp contract(off)
  const int si = p >> 2, oi = p & 3;
  const float s = (si == 0) ? 0.25f : (si == 1 ? 0.5f : 1.0f);
  const float dx = s * (RP[j][0] - cx);
  const float dy = s * (RP[j][1] - cy);
  const float rx = (oi == 0) ? dx : (oi == 1 ? -dy : (oi == 2 ? -dx : dy));
  const float ry = (oi == 0) ? dy : (oi == 1 ? dx : (oi == 2 ? -dy : -dx));
  return make_float2(cx + rx, cy + ry);
}

// ============ K1: decisions -> labels (9.4 MB) + code bytes (0.77 MB, d_ws) ====
__global__ __launch_bounds__(256, 5) void k_decide(const float* __restrict__ gt,
                                                   const int* __restrict__ ht,
                                                   float* __restrict__ ol,
                                                   char* __restrict__ codes) {
  __shared__ float2 sb2[252];
  __shared__ float4 sg4[21];
  __shared__ float2 sv2[21];
  __shared__ float sden[2], srden[2], snv[2];
  __shared__ int sht[2];
  __shared__ int scc[256];

  const int tid = threadIdx.x;
  const int b = blockIdx.x / ABLOCKS;
  const int ab = blockIdx.x % ABLOCKS;
  const int a0 = ab * 256;

  if (tid < 252) {
    float cx, cy; ref_center(cx, cy);
    sb2[tid] = base_pt(tid / 21, tid % 21, cx, cy);
  }
  if (tid < 21) {
    const float* g0 = gt + b * 126 + tid * 3;
    const float* g1 = g0 + 63;
    sg4[tid] = make_float4(g0[0], g0[1], g1[0], g1[1]);
    sv2[tid] = make_float2((g0[2] > 0.0f) ? 1.0f : 0.0f,
                           (g1[2] > 0.0f) ? 1.0f : 0.0f);
  }
  if (tid == 252 || tid == 253) {   // per-hand area/denominator
    const int h = tid - 252;
    const float* g = gt + b * 126 + h * 63;
    float mnx = g[0], mxx = g[0], mny = g[1], mxy = g[1];
    float nv = (g[2] > 0.0f) ? 1.0f : 0.0f;
    for (int j = 1; j < 21; ++j) {
      float x = g[j * 3], y = g[j * 3 + 1];
      mnx = fminf(mnx, x); mxx = fmaxf(mxx, x);
      mny = fminf(mny, y); mxy = fmaxf(mxy, y);
      nv += (g[j * 3 + 2] > 0.0f) ? 1.0f : 0.0f;
    }
    const float area = (mxx - mnx) * (mxy - mny);
    const float s2 = fmaxf(area, 1.0f);
    const float den = (2.0f * s2) * 0.01f;   // 2*s2*k2, k2 -> 0.01f in f32
    sden[h] = den;
    srden[h] = -1.0f / den;
    snv[h] = fmaxf(nv, 1.0f);
  }
  if (tid == 254 || tid == 255) sht[tid - 254] = ht[b * 2 + (tid - 254)];
  __syncthreads();

  const int a = a0 + tid;
  const int p = a % 12;
  const int kc = a / 12;
  const float shx = 4.0f * (float)(kc & 63);
  const float shy = 4.0f * (float)(kc >> 6);
  const int pb = p * 21;

  // ---- fast path: __expf-based sims ----
  const float rd0 = srden[0], rd1 = srden[1];
  bool inside = true;
  float s0f = 0.0f, s1f = 0.0f;
  #pragma unroll
  for (int j = 0; j < 21; ++j) {
    #pragma clang fp contract(off)
    const float2 bpv = sb2[pb + j];
    const float anx = bpv.x + shx;
    const float any = bpv.y + shy;
    inside = inside && (anx >= 0.0f) && (any >= 0.0f) &&
                       (anx < 256.0f) && (any < 256.0f);
    const float4 g = sg4[j];
    const float2 v = sv2[j];
    const float dx0 = anx - g.x, dy0 = any - g.y;
    const float dx1 = anx - g.z, dy1 = any - g.w;
    s0f += __expf((dx0 * dx0 + dy0 * dy0) * rd0) * v.x;
    s1f += __expf((dx1 * dx1 + dy1 * dy1) * rd1) * v.y;
  }
  float sim0 = s0f / snv[0];
  float sim1 = s1f / snv[1];
  const float mxf = fmaxf(sim0, sim1);
  const bool need_exact = (fabsf(mxf - 0.5f) < EPS) ||
                          ((mxf > 0.5f - EPS) && (fabsf(sim0 - sim1) < EPS));

  if (__builtin_expect(need_exact, 0)) {
    // ---- exact fallback: bit-identical to round-1 (double exp, numpy tree) ----
    #pragma clang fp contract(off)
    float q0[8], q1[8];
    #pragma unroll
    for (int j = 0; j < 16; ++j) {
      const float2 bpv = sb2[pb + j];
      const float ax = bpv.x + shx, ay = bpv.y + shy;
      const float4 g = sg4[j];
      const float2 v = sv2[j];
      float dx0 = ax - g.x, dy0 = ay - g.y;
      float d20 = dx0 * dx0 + dy0 * dy0;
      float t0 = (float)::exp((double)(-d20 / sden[0])) * v.x;
      float dx1 = ax - g.z, dy1 = ay - g.w;
      float d21 = dx1 * dx1 + dy1 * dy1;
      float t1 = (float)::exp((double)(-d21 / sden[1])) * v.y;
      if (j < 8) { q0[j] = t0; q1[j] = t1; }
      else       { q0[j - 8] += t0; q1[j - 8] += t1; }
    }
    float s0 = ((q0[0] + q0[1]) + (q0[2] + q0[3])) + ((q0[4] + q0[5]) + (q0[6] + q0[7]));
    float s1 = ((q1[0] + q1[1]) + (q1[2] + q1[3])) + ((q1[4] + q1[5]) + (q1[6] + q1[7]));
    #pragma unroll
    for (int j = 16; j < 21; ++j) {
      const float2 bpv = sb2[pb + j];
      const float ax = bpv.x + shx, ay = bpv.y + shy;
      const float4 g = sg4[j];
      const float2 v = sv2[j];
      float dx0 = ax - g.x, dy0 = ay - g.y;
      float d20 = dx0 * dx0 + dy0 * dy0;
      s0 += (float)::exp((double)(-d20 / sden[0])) * v.x;
      float dx1 = ax - g.z, dy1 = ay - g.w;
      float d21 = dx1 * dx1 + dy1 * dy1;
      s1 += (float)::exp((double)(-d21 / sden[1])) * v.y;
    }
    sim0 = s0 / snv[0];
    sim1 = s1 / snv[1];
  }

  const int am = (sim1 > sim0) ? 1 : 0;   // argmax: first index wins ties
  const float mx = fmaxf(sim0, sim1);
  const bool pos = mx > 0.5f;
  const bool right = (am == 0) && pos && (sht[0] == 1) && inside;
  const bool left  = (am == 1) && pos && (sht[1] == 1) && inside;

  int c;            // -1 outside, 0 neg, 1 right, 2 left
  if (!inside)      c = -1;
  else if (right)   c = 1;
  else if (left)    c = 2;
  else              c = 0;
  scc[tid] = c;
  codes[b * NA + a] = (char)c;
  __syncthreads();

  // ---- labels: 192 float4 per block ----
  if (tid < 192) {
    float* lb = ol + ((size_t)b * NA + a0) * 3;
    float r[4];
    #pragma unroll
    for (int k = 0; k < 4; ++k) {
      const int q = tid * 4 + k;
      const int al = q / 3;
      const int rr = q - al * 3;
      const int cc = scc[al];
      float v;
      if (cc < 0)       v = -1.0f;
      else if (rr == 0) v = (cc == 2) ? 1.0f : 0.0f;   // left
      else if (rr == 1) v = (cc == 0) ? 1.0f : 0.0f;   // neg
      else              v = (cc == 1) ? 1.0f : 0.0f;   // right
      r[k] = v;
    }
    st4(lb + tid * 4, r[0], r[1], r[2], r[3]);
  }
}

// decode within-batch float2-element e -> (value for offsets) given code table
__device__ __forceinline__ float2 off_elem(int e, const char* __restrict__ codes,
                                           int cb, const float2* sb2,
                                           const float4* sg) {
  #pragma clang fp contract(off)
  const int al = e / 21;               // const-div magic
  const int j  = e - al * 21;
  const int kc = al / 12;              // const-div magic
  const int p  = al - kc * 12;
  const float shx = 4.0f * (float)(kc & 63);
  const float shy = 4.0f * (float)(kc >> 6);
  const float2 bpv = sb2[p * 21 + j];
  const float anx = bpv.x + shx, any = bpv.y + shy;
  const int cc = (int)codes[cb + al];
  const float4 g = sg[j];
  const bool has = (cc == 1) || (cc == 2);
  float tx = (cc == 2) ? g.z : g.x;
  float ty = (cc == 2) ? g.w : g.y;
  tx = has ? tx : 0.0f; ty = has ? ty : 0.0f;
  return make_float2((cc >= 0) ? (tx - anx) : 0.0f,
                     (cc >= 0) ? (ty - any) : 0.0f);
}

__device__ __forceinline__ float2 anc_elem(int e, const float2* sb2) {
  const int al = e / 21;
  const int j  = e - al * 21;
  const int kc = al / 12;
  const int p  = al - kc * 12;
  const float shx = 4.0f * (float)(kc & 63);
  const float shy = 4.0f * (float)(kc >> 6);
  const float2 bpv = sb2[p * 21 + j];
  return make_float2(bpv.x + shx, bpv.y + shy);
}

// ============ K2: fill-style streamer — flat grid-stride sweeping front ====
__global__ __launch_bounds__(256, 6) void k_stream(const float* __restrict__ gt,
                                                   const char* __restrict__ codes,
                                                   float* __restrict__ oa,
                                                   float* __restrict__ oins,
                                                   float* __restrict__ oo) {
  __shared__ float2 sb2[252];
  __shared__ float4 sgall[NB * 21];   // per-batch target xy (x0,y0,x1,y1)

  const int tid = threadIdx.x;
  if (tid < 252) {
    float cx, cy; ref_center(cx, cy);
    sb2[tid] = base_pt(tid / 21, tid % 21, cx, cy);
  }
  for (int t = tid; t < NB * 21; t += 256) {
    const int bb = t / 21, j = t - bb * 21;
    const float* g0 = gt + bb * 126 + j * 3;
    const float* g1 = g0 + 63;
    sgall[t] = make_float4(g0[0], g0[1], g1[0], g1[1]);
  }
  __syncthreads();

  const int G = gridDim.x * 256;
  const int g0i = blockIdx.x * 256 + tid;

  // ---- offsets: one dense sweeping front over 132 MB ----
  for (int q = g0i; q < OF4; q += G) {
    const int b = q / OF4B;            // const-div magic
    const int r = q - b * OF4B;
    const int e0 = 2 * r;
    const float2 r0 = off_elem(e0,     codes, b * NA, sb2, sgall + b * 21);
    const float2 r1 = off_elem(e0 + 1, codes, b * NA, sb2, sgall + b * 21);
    st4(oo + (size_t)q * 4, r0.x, r0.y, r1.x, r1.y);
  }

  // ---- anchors: sweeping front over 8.25 MB ----
  for (int q = g0i; q < AF4; q += G) {
    const int e0 = 2 * q;
    const float2 r0 = anc_elem(e0, sb2);
    const float2 r1 = anc_elem(e0 + 1, sb2);
    st4(oa + (size_t)q * 4, r0.x, r0.y, r1.x, r1.y);
  }

  // ---- inside: from b=0 code row (b-independent) ----
  for (int q = g0i; q < IF4; q += G) {
    const char4 c4 = *reinterpret_cast<const char4*>(codes + q * 4);
    st4(oins + (size_t)q * 4,
        (c4.x >= 0) ? 1.0f : 0.0f,
        (c4.y >= 0) ? 1.0f : 0.0f,
        (c4.z >= 0) ? 1.0f : 0.0f,
        (c4.w >= 0) ? 1.0f : 0.0f);
  }
}

extern "C" void kernel_launch(void* const* d_in, const int* in_sizes, int n_in,
                              void* d_out, int out_size, void* d_ws, size_t ws_size,
                              hipStream_t stream) {
  (void)in_sizes; (void)n_in; (void)ws_size; (void)out_size;
  const float* gt = (const float*)d_in[0];   // (16,42,3) f32
  const int* ht = (const int*)d_in[1];       // (16,2) i32
  float* out = (float*)d_out;
  float* out_anchors = out;                                   // NA*42
  float* out_inside  = out + (size_t)NA * 42;                 // NA
  float* out_labels  = out + (size_t)NA * 43;                 // NB*NA*3
  float* out_offsets = out_labels + (size_t)NB * NA * 3;      // NB*NA*42
  char* codes = (char*)d_ws;                                  // NB*NA bytes

  hipLaunchKernelGGL(k_decide, dim3(NB * ABLOCKS), dim3(256), 0, stream,
                     gt, ht, out_labels, codes);
  hipLaunchKernelGGL(k_stream, dim3(2048), dim3(256), 0, stream,
                     gt, codes, out_anchors, out_inside, out_offsets);
}